// Round 7
// baseline (1065.732 us; speedup 1.0000x reference)
//
#include <hip/hip_runtime.h>
#include <math.h>

#define BB 2
#define TT 2048
#define DD 1024
#define HH 16
#define DH 64
#define WW 256
#define NN 256
#define ROWS (BB*TT)             // 4096
#define ROWSZ ((size_t)ROWS*DD)  // 4,194,304

typedef unsigned short u16;
typedef __attribute__((ext_vector_type(8))) short short8;
typedef __attribute__((ext_vector_type(4))) float f32x4;

__device__ __forceinline__ float bf2f(u16 h) {
    union { unsigned int u; float f; } c; c.u = ((unsigned int)h) << 16; return c.f;
}
__device__ __forceinline__ u16 f2bf(float f) {
    union { float f; unsigned int u; } c; c.f = f;
    unsigned int r = c.u + 0x7fffu + ((c.u >> 16) & 1u);
    return (u16)(r >> 16);
}

__device__ __forceinline__ void gld16(const void* g, void* l) {
    __builtin_amdgcn_global_load_lds(
        (const __attribute__((address_space(1))) void*)g,
        (__attribute__((address_space(3))) void*)l, 16, 0, 0);
}

// ---------------- LayerNorm (fp32 in -> bf16 out) ----------------
__global__ __launch_bounds__(256) void ln_kernel(const float* __restrict__ x,
                                                 const float* __restrict__ g,
                                                 const float* __restrict__ b,
                                                 u16* __restrict__ out) {
    int row = blockIdx.x;
    int t = threadIdx.x;
    const float4* xr = (const float4*)(x + (size_t)row * DD);
    float4 v4 = xr[t];
    float s  = v4.x + v4.y + v4.z + v4.w;
    float s2 = v4.x*v4.x + v4.y*v4.y + v4.z*v4.z + v4.w*v4.w;
    #pragma unroll
    for (int o = 32; o > 0; o >>= 1) { s += __shfl_xor(s, o); s2 += __shfl_xor(s2, o); }
    __shared__ float red[2][4];
    int wid = t >> 6, lane = t & 63;
    if (lane == 0) { red[0][wid] = s; red[1][wid] = s2; }
    __syncthreads();
    s  = red[0][0] + red[0][1] + red[0][2] + red[0][3];
    s2 = red[1][0] + red[1][1] + red[1][2] + red[1][3];
    float mean = s * (1.0f / DD);
    float var  = s2 * (1.0f / DD) - mean * mean;
    float inv  = rsqrtf(var + 1e-5f);
    const float4* g4 = (const float4*)g;
    const float4* b4 = (const float4*)b;
    float4 gg = g4[t], bb = b4[t];
    float o0 = (v4.x - mean) * inv * gg.x + bb.x;
    float o1 = (v4.y - mean) * inv * gg.y + bb.y;
    float o2 = (v4.z - mean) * inv * gg.z + bb.z;
    float o3 = (v4.w - mean) * inv * gg.w + bb.w;
    uint2 packed;
    packed.x = (unsigned)f2bf(o0) | ((unsigned)f2bf(o1) << 16);
    packed.y = (unsigned)f2bf(o2) | ((unsigned)f2bf(o3) << 16);
    *(uint2*)(out + (size_t)row * DD + 4 * t) = packed;
}

// ---------------- all weight transpose-converts in ONE launch ----------------
__global__ __launch_bounds__(256) void tconv_all(
    const float* __restrict__ wq, const float* __restrict__ wk,
    const float* __restrict__ wv, const float* __restrict__ wg,
    const float* __restrict__ Bw, const float* __restrict__ wo,
    const float* __restrict__ Cw, const float* __restrict__ w1,
    const float* __restrict__ w2,
    u16* __restrict__ wqkvgut, u16* __restrict__ wot, u16* __restrict__ cwt,
    u16* __restrict__ w1t, u16* __restrict__ w2t) {
    int tile = blockIdx.x;
    const float* src; u16* dst; int K, N, tx, ty;
    if (tile < 4096) {
        int seg = tile >> 10, tl = tile & 1023;
        src = (seg == 0) ? wq : (seg == 1) ? wk : (seg == 2) ? wv : wg;
        dst = wqkvgut + (size_t)seg * 1024 * 1024;
        K = 1024; N = 1024; tx = tl & 31; ty = tl >> 5;
    } else if (tile < 4352) {
        int tl = tile - 4096;
        src = Bw; dst = wqkvgut + (size_t)4096 * 1024;
        K = 1024; N = 256; tx = tl & 7; ty = tl >> 3;
    } else if (tile < 5376) {
        int tl = tile - 4352;
        src = wo; dst = wot; K = 1024; N = 1024; tx = tl & 31; ty = tl >> 5;
    } else if (tile < 5632) {
        int tl = tile - 5376;
        src = Cw; dst = cwt; K = 256; N = 1024; tx = tl & 31; ty = tl >> 5;
    } else if (tile < 9728) {
        int tl = tile - 5632;
        src = w1; dst = w1t; K = 1024; N = 4096; tx = tl & 127; ty = tl >> 7;
    } else {
        int tl = tile - 9728;
        src = w2; dst = w2t; K = 4096; N = 1024; tx = tl & 31; ty = tl >> 5;
    }
    __shared__ float ts[32][33];
    int n0 = tx * 32, k0 = ty * 32;
    int tc = threadIdx.x & 31, tr = threadIdx.x >> 5;
    #pragma unroll
    for (int i = tr; i < 32; i += 8)
        ts[i][tc] = src[(size_t)(k0 + i) * N + n0 + tc];
    __syncthreads();
    #pragma unroll
    for (int i = tr; i < 32; i += 8)
        dst[(size_t)(n0 + i) * K + k0 + tc] = f2bf(ts[tc][i]);
}

// ---------------- bias concat for fused QKVG gemm ----------------
__global__ __launch_bounds__(256) void bias_init(const float* __restrict__ bq,
                                                 const float* __restrict__ bk,
                                                 const float* __restrict__ bv,
                                                 const float* __restrict__ bg,
                                                 float* __restrict__ dst) {
    int i = blockIdx.x * 256 + threadIdx.x;
    if (i >= 4096) return;
    float v;
    if (i < 1024) v = bq[i];
    else if (i < 2048) v = bk[i - 1024];
    else if (i < 3072) v = bv[i - 2048];
    else v = bg[i - 3072];
    dst[i] = v;
}

// ============ m201-template 8-phase 256x256 MFMA GEMM core (BK=64) ============
// 512 threads = 8 waves (2M x 4N); per-wave output 128x64 = acc[8][4] f32x4.
// LDS: 2 dbufs x (A 256x64 + B 256x64) bf16 = 128 KiB (1 block/CU).
// Iteration = 2 K-tiles (t0=2i in dbuf0, t1=2i+1 in dbuf1), 8 phases.
// Phase q of a tile computes m-frags {2q,2q+1} x 4 n-frags x 2 ks = 16 MFMA;
// reads A rows 64q..64q+63 (B: all rows, at q=0 only).
// Stage schedule (one 128-row half-tile = 2x gld16 per phase), WAR-safe by
// the phase read footprints:
//   ph0: A(t1)h1   ph1: B(t0+2)h0  ph2: B(t0+2)h1  ph3: A(t0+2)h0
//   ph4: A(t0+2)h1 ph5: B(t1+2)h0  ph6: B(t1+2)h1  ph7: A(t1+2)h0
// Counted waits (per-wave vmcnt, collective via following barrier), traced:
//   prologue: stage B0h0,B0h1,A0h0,A0h1,B1h0,B1h1,A1h0 (14 loads), vmcnt(6)
//   steady  : ph1 vmcnt(10), ph3 vmcnt(8), ph5 vmcnt(10), ph7 vmcnt(8)
//   last it : ph1 vmcnt(8),  ph3 vmcnt(2), ph5 vmcnt(0)
// Every load gets >=4 phases of slack; vmcnt never drains below 8 in steady
// loop (T4). Rule #18: sched_barrier(0) after each lgkmcnt(0).
// Swizzle (R2-verified, 0 conflicts): 128B row = 8 chunks of 16B; chunk j of
// row r at LDS pos p = j ^ (r&7); reads csw = ((ks*4+jq) ^ (rq&7))<<4;
// stage source pre-swizzled (8 consecutive lanes cover one full row).

#define MFMA_BF16 __builtin_amdgcn_mfma_f32_16x16x32_bf16
#define WAITN(n) asm volatile("s_waitcnt vmcnt(" #n ")" ::: "memory")

#define STAGE(isB, tk, h) do { if ((tk) < kiters) { \
    const char* gs_ = ((isB) ? gB0 : gA0) + (size_t)(tk) * 128 + (size_t)(h) * hstride; \
    char* ld_ = ((isB) ? Bls : Als) + (((tk) & 1) << 15) + ((h) << 14) + (t << 4); \
    gld16(gs_, ld_); gld16(gs_ + rowskip, ld_ + 8192); } } while (0)

#define PHASE(Q, DB, STG, WT) { \
    const char* Ab_ = Als + ((DB) << 15); \
    int ra_ = ((Q) * 64 + wm * 16 + rq) * 128; \
    short8 af0 = *(const short8*)(Ab_ + ra_ + csw0); \
    short8 af1 = *(const short8*)(Ab_ + ra_ + csw1); \
    short8 af2 = *(const short8*)(Ab_ + ra_ + 4096 + csw0); \
    short8 af3 = *(const short8*)(Ab_ + ra_ + 4096 + csw1); \
    if ((Q) == 0) { \
        const char* Bb_ = Bls + ((DB) << 15); \
        _Pragma("unroll") \
        for (int n_ = 0; n_ < 4; n_++) { \
            bfr[n_][0] = *(const short8*)(Bb_ + rowB[n_] + csw0); \
            bfr[n_][1] = *(const short8*)(Bb_ + rowB[n_] + csw1); \
        } \
    } \
    STG; \
    WT; \
    __builtin_amdgcn_s_barrier(); \
    asm volatile("s_waitcnt lgkmcnt(0)" ::: "memory"); \
    __builtin_amdgcn_sched_barrier(0); \
    __builtin_amdgcn_s_setprio(1); \
    _Pragma("unroll") \
    for (int n_ = 0; n_ < 4; n_++) { \
        acc[2*(Q)][n_]   = MFMA_BF16(af0, bfr[n_][0], acc[2*(Q)][n_], 0, 0, 0); \
        acc[2*(Q)][n_]   = MFMA_BF16(af1, bfr[n_][1], acc[2*(Q)][n_], 0, 0, 0); \
        acc[2*(Q)+1][n_] = MFMA_BF16(af2, bfr[n_][0], acc[2*(Q)+1][n_], 0, 0, 0); \
        acc[2*(Q)+1][n_] = MFMA_BF16(af3, bfr[n_][1], acc[2*(Q)+1][n_], 0, 0, 0); \
    } \
    __builtin_amdgcn_s_setprio(0); \
    __builtin_amdgcn_s_barrier(); }

#define NOSTG (void)0

__device__ __forceinline__ void gemm_core_8p(const u16* __restrict__ A,
                                             const u16* __restrict__ Bt,
                                             int K, int kiters, int kofs,
                                             int m0, int n0,
                                             char* Als, char* Bls,
                                             int t, f32x4 acc[8][4]) {
    int lane = t & 63, wid = t >> 6;
    int wm = wid >> 2, wn = wid & 3;
    int jq = lane >> 4, rq = lane & 15;
    int csw0 = (jq ^ (rq & 7)) << 4;
    int csw1 = ((4 + jq) ^ (rq & 7)) << 4;
    int rowB[4];
    #pragma unroll
    for (int n = 0; n < 4; n++) rowB[n] = (wn * 64 + n * 16 + rq) * 128;

    // staging addresses: slot0 row rl (0..63), slot1 row rl+64; same chunk j
    int rl = t >> 3, p8 = t & 7;
    int jg = p8 ^ (rl & 7);
    const char* gA0 = (const char*)(A + (size_t)(m0 + rl) * K + kofs) + jg * 16;
    const char* gB0 = (const char*)(Bt + (size_t)(n0 + rl) * K + kofs) + jg * 16;
    size_t rowskip = (size_t)64 * K * 2;
    size_t hstride = (size_t)128 * K * 2;

    short8 bfr[4][2];

    // prologue: B0h0,B0h1,A0h0,A0h1,B1h0,B1h1,A1h0 ; drain first 4 stages
    STAGE(1, 0, 0); STAGE(1, 0, 1); STAGE(0, 0, 0); STAGE(0, 0, 1);
    STAGE(1, 1, 0); STAGE(1, 1, 1); STAGE(0, 1, 0);
    WAITN(6);
    __builtin_amdgcn_s_barrier();

    int NI = kiters >> 1;
    for (int i = 0; i < NI; i++) {
        int t1 = 2 * i + 1;
        if (i + 1 < NI) {
            PHASE(0, 0, STAGE(0, t1, 1),      NOSTG)
            PHASE(1, 0, STAGE(1, t1 + 1, 0),  WAITN(10))
            PHASE(2, 0, STAGE(1, t1 + 1, 1),  NOSTG)
            PHASE(3, 0, STAGE(0, t1 + 1, 0),  WAITN(8))
            PHASE(0, 1, STAGE(0, t1 + 1, 1),  NOSTG)
            PHASE(1, 1, STAGE(1, t1 + 2, 0),  WAITN(10))
            PHASE(2, 1, STAGE(1, t1 + 2, 1),  NOSTG)
            PHASE(3, 1, STAGE(0, t1 + 2, 0),  WAITN(8))
        } else {
            PHASE(0, 0, STAGE(0, t1, 1), NOSTG)
            PHASE(1, 0, NOSTG, WAITN(8))
            PHASE(2, 0, NOSTG, NOSTG)
            PHASE(3, 0, NOSTG, WAITN(2))
            PHASE(0, 1, NOSTG, NOSTG)
            PHASE(1, 1, NOSTG, WAITN(0))
            PHASE(2, 1, NOSTG, NOSTG)
            PHASE(3, 1, NOSTG, NOSTG)
        }
    }
}

// ---------------- generic 256^2 GEMM kernel (XCD-swizzled 1-D grid) ----------------
// grid.x = mtiles*ntiles (divisible by 8); grid.y = K-split slices.
template<int ACT, bool OUTBF, bool SPLIT>
__global__ __launch_bounds__(512, 2) void mgemm64(const u16* __restrict__ A,
                                                  const u16* __restrict__ Bt,
                                                  const float* __restrict__ bias,
                                                  void* __restrict__ C,
                                                  int M, int N, int K, int Kslice,
                                                  int mtiles, int ntiles, int PM, int PN) {
    __shared__ __align__(16) char LDS[131072];
    char* Als = LDS;
    char* Bls = LDS + 65536;
    int t = threadIdx.x;
    int l = blockIdx.x;
    int xcd = l & 7, li = l >> 3;
    int rm = mtiles / PM, rn = ntiles / PN;
    int xm = xcd % PM, xn = xcd / PM;
    int mt = xm * rm + li % rm;
    int nt = xn * rn + li / rm;
    int m0 = mt * 256, n0 = nt * 256;
    int z = SPLIT ? blockIdx.y : 0;
    f32x4 acc[8][4];
    #pragma unroll
    for (int i = 0; i < 8; i++)
        #pragma unroll
        for (int j = 0; j < 4; j++)
            acc[i][j] = (f32x4){0.f, 0.f, 0.f, 0.f};
    gemm_core_8p(A, Bt, K, Kslice >> 6, z * Kslice, m0, n0, Als, Bls, t, acc);

    int lane = t & 63, wid = t >> 6;
    int wm = wid >> 2, wn = wid & 3;
    int jq = lane >> 4, rq = lane & 15;
    u16* Cb = OUTBF ? ((u16*)C + (SPLIT ? (size_t)z * M * N : (size_t)0)) : nullptr;
    float* Cf = (float*)C;
    #pragma unroll
    for (int i = 0; i < 8; i++) {
        int rowb = m0 + i * 32 + wm * 16 + jq * 4;
        #pragma unroll
        for (int jn = 0; jn < 4; jn++) {
            int col = n0 + wn * 64 + jn * 16 + rq;
            float bv = bias ? bias[col] : 0.f;
            #pragma unroll
            for (int rr = 0; rr < 4; rr++) {
                float v = acc[i][jn][rr] + bv;
                if (ACT == 1) v = 0.5f * v * (1.0f + erff(v * 0.70710678118654752f));
                size_t off = (size_t)(rowb + rr) * N + col;
                if (OUTBF) Cb[off] = f2bf(v);
                else Cf[off] = v;
            }
        }
    }
}

// ---------------- u partial reduce: u = sum_z(parts[z]) (bf16) ----------------
__global__ __launch_bounds__(256) void ureduce(const u16* __restrict__ p,
                                               u16* __restrict__ o) {
    size_t i2 = (size_t)blockIdx.x * 256 + threadIdx.x;  // uint2 = 4 bf16
    float a0 = 0.f, a1 = 0.f, a2 = 0.f, a3 = 0.f;
    #pragma unroll
    for (int z = 0; z < 4; z++) {
        uint2 v = ((const uint2*)(p + (size_t)z * 1048576))[i2];
        a0 += bf2f((u16)(v.x & 0xffff));
        a1 += bf2f((u16)(v.x >> 16));
        a2 += bf2f((u16)(v.y & 0xffff));
        a3 += bf2f((u16)(v.y >> 16));
    }
    uint2 r;
    r.x = (unsigned)f2bf(a0) | ((unsigned)f2bf(a1) << 16);
    r.y = (unsigned)f2bf(a2) | ((unsigned)f2bf(a3) << 16);
    ((uint2*)o)[i2] = r;
}

// ---------------- fused wo + cw projection (grid.z selects job) ----------------
__global__ __launch_bounds__(512, 2) void proj3(const u16* __restrict__ ao,
                                                const u16* __restrict__ states,
                                                const u16* __restrict__ wot,
                                                const u16* __restrict__ cwt,
                                                const float* __restrict__ bo,
                                                u16* __restrict__ ya0,
                                                u16* __restrict__ ya1,
                                                float* __restrict__ ys) {
    __shared__ __align__(16) char LDS[131072];
    char* Als = LDS;
    char* Bls = LDS + 65536;
    int t = threadIdx.x;
    int m0 = blockIdx.y * 256, n0 = blockIdx.x * 256;
    int z = blockIdx.z;
    const u16* A; const u16* Bt; int K, kofs, kiters;
    if (z < 2) { A = ao; Bt = wot; K = 1024; kofs = z * 512; kiters = 8; }
    else       { A = states; Bt = cwt; K = 256; kofs = 0; kiters = 4; }
    f32x4 acc[8][4];
    #pragma unroll
    for (int i = 0; i < 8; i++)
        #pragma unroll
        for (int j = 0; j < 4; j++)
            acc[i][j] = (f32x4){0.f, 0.f, 0.f, 0.f};
    gemm_core_8p(A, Bt, K, kiters, kofs, m0, n0, Als, Bls, t, acc);

    int lane = t & 63, wid = t >> 6;
    int wm = wid >> 2, wn = wid & 3;
    int jq = lane >> 4, rq = lane & 15;
    u16* dst = (z == 0) ? ya0 : ya1;
    #pragma unroll
    for (int i = 0; i < 8; i++) {
        int rowb = m0 + i * 32 + wm * 16 + jq * 4;
        #pragma unroll
        for (int jn = 0; jn < 4; jn++) {
            int col = n0 + wn * 64 + jn * 16 + rq;
            float bv = (z == 0) ? bo[col] : 0.f;
            #pragma unroll
            for (int rr = 0; rr < 4; rr++) {
                float v = acc[i][jn][rr] + bv;
                size_t off = (size_t)(rowb + rr) * DD + col;
                if (z < 2) dst[off] = f2bf(v);
                else ys[off] = v;
            }
        }
    }
}

// ---------------- MFMA sliding-window attention + SSM scan (merged launch) ----------------
// QKVG rows are 4096 wide (Q|K|V|G); u is a separate [ROWS][256] bf16 buffer.
__global__ __launch_bounds__(256) void attn_scan(const u16* __restrict__ QKVG,
                                                 const u16* __restrict__ ubuf,
                                                 u16* __restrict__ O,
                                                 const float* __restrict__ Assm,
                                                 const float* __restrict__ s0,
                                                 u16* __restrict__ states,
                                                 float* __restrict__ s_out) {
    __shared__ __align__(16) short Qs[8][64][8];
    __shared__ __align__(16) short Ks[8][64][8];
    __shared__ __align__(16) short Vt[64][72];
    __shared__ __align__(16) short Ps[4][16][72];

    if (blockIdx.x >= 1024) {
        int idx = (blockIdx.x - 1024) * 256 + threadIdx.x;
        int n = idx & 255;
        int c = (idx >> 8) & 31;
        int b = idx >> 13;
        float alpha = tanhf(Assm[n]);
        int t0 = c * 64;
        float s = (c == 0) ? s0[b * NN + n] : 0.f;
        const u16* up = ubuf + (size_t)(b * TT) * NN + n;
        if (c > 0) {
            #pragma unroll
            for (int k = 8; k >= 1; k--)
                s = alpha * s + bf2f(up[(size_t)(t0 - k) * NN]);
        }
        u16* sp = states + (size_t)(b * TT) * NN + n;
        for (int t = t0; t < t0 + 64; t++) {
            s = alpha * s + bf2f(up[(size_t)t * NN]);
            sp[(size_t)t * NN] = f2bf(s);
        }
        if (c == 31) s_out[b * NN + n] = s;
        return;
    }

    int blk = blockIdx.x;
    int qb = blk & 31;
    int h  = (blk >> 5) & 15;
    int b  = blk >> 9;
    int q0 = qb * 64;
    int t = threadIdx.x, lane = t & 63, w = t >> 6;
    int rq = lane & 15, jq = lane >> 4;

    const size_t RS = 4096;

    #pragma unroll
    for (int i = 0; i < 2; i++) {
        int c = 2 * w + i;
        const u16* g = QKVG + (size_t)(b * TT + q0 + lane) * RS + h * 64 + c * 8;
        gld16(g, (char*)Qs + c * 1024);
    }

    f32x4 Oa[4];
    #pragma unroll
    for (int tj = 0; tj < 4; tj++) Oa[tj] = (f32x4){0.f, 0.f, 0.f, 0.f};
    float mrow[4], lrow[4];
    #pragma unroll
    for (int r = 0; r < 4; r++) { mrow[r] = -1e30f; lrow[r] = 0.f; }

    int c0 = 4 - (q0 >> 6); if (c0 < 0) c0 = 0;

    for (int ci = c0; ci < 5; ci++) {
        int kbase = q0 - 256 + ci * 64;
        #pragma unroll
        for (int i = 0; i < 2; i++) {
            int c = 2 * w + i;
            const u16* g = QKVG + (size_t)(b * TT + kbase + lane) * RS + 1024 + h * 64 + c * 8;
            gld16(g, (char*)Ks + c * 1024);
        }
        #pragma unroll
        for (int i = 0; i < 2; i++) {
            int dhg = i * 4 + w;
            uint4 v = *(const uint4*)(QKVG + (size_t)(b * TT + kbase + lane) * RS + 2048 + h * 64 + dhg * 8);
            const u16* pv = (const u16*)&v;
            #pragma unroll
            for (int j = 0; j < 8; j++) Vt[dhg * 8 + j][lane] = (short)pv[j];
        }
        __syncthreads();

        short8 qf[2];
        #pragma unroll
        for (int s = 0; s < 2; s++)
            qf[s] = *(const short8*)&Qs[4 * s + jq][w * 16 + rq][0];

        f32x4 S[4];
        #pragma unroll
        for (int tj = 0; tj < 4; tj++) S[tj] = (f32x4){0.f, 0.f, 0.f, 0.f};
        #pragma unroll
        for (int s = 0; s < 2; s++)
            #pragma unroll
            for (int tj = 0; tj < 4; tj++) {
                short8 kf = *(const short8*)&Ks[4 * s + jq][tj * 16 + rq][0];
                S[tj] = __builtin_amdgcn_mfma_f32_16x16x32_bf16(qf[s], kf, S[tj], 0, 0, 0);
            }

        #pragma unroll
        for (int r = 0; r < 4; r++) {
            int q = q0 + w * 16 + jq * 4 + r;
            float sv[4];
            #pragma unroll
            for (int tj = 0; tj < 4; tj++) {
                int kp = kbase + tj * 16 + rq;
                float x = S[tj][r] * 0.125f;
                bool valid = (kp <= q) && (kp > q - WW);
                sv[tj] = valid ? x : -1e30f;
            }
            float cm = fmaxf(fmaxf(sv[0], sv[1]), fmaxf(sv[2], sv[3]));
            #pragma unroll
            for (int o = 1; o < 16; o <<= 1) cm = fmaxf(cm, __shfl_xor(cm, o));
            float mn = fmaxf(mrow[r], cm);
            bool any = mn > -1e29f;
            float al = any ? __expf(mrow[r] - mn) : 1.f;
            float ps = 0.f;
            #pragma unroll
            for (int tj = 0; tj < 4; tj++) {
                float p = any ? __expf(sv[tj] - mn) : 0.f;
                ps += p;
                Ps[w][jq * 4 + r][tj * 16 + rq] = (short)f2bf(p);
            }
            #pragma unroll
            for (int o = 1; o < 16; o <<= 1) ps += __shfl_xor(ps, o);
            lrow[r] = lrow[r] * al + ps;
            mrow[r] = mn;
            #pragma unroll
            for (int tj = 0; tj < 4; tj++) Oa[tj][r] *= al;
        }

        #pragma unroll
        for (int s = 0; s < 2; s++) {
            short8 pf = *(const short8*)&Ps[w][rq][32 * s + 8 * jq];
            #pragma unroll
            for (int tj = 0; tj < 4; tj++) {
                short8 vf = *(const short8*)&Vt[tj * 16 + rq][32 * s + 8 * jq];
                Oa[tj] = __builtin_amdgcn_mfma_f32_16x16x32_bf16(pf, vf, Oa[tj], 0, 0, 0);
            }
        }
        __syncthreads();
    }

    #pragma unroll
    for (int r = 0; r < 4; r++) {
        int q = q0 + w * 16 + jq * 4 + r;
        float inv = 1.f / lrow[r];
        #pragma unroll
        for (int tj = 0; tj < 4; tj++)
            O[(size_t)(b * TT + q) * DD + h * 64 + tj * 16 + rq] = f2bf(Oa[tj][r] * inv);
    }
}

// ---------------- fused gate/residual + LayerNorm2 ----------------
__global__ __launch_bounds__(256) void fuse_ln2(const float* __restrict__ x,
                                                const u16* __restrict__ QKVG,
                                                const u16* __restrict__ ya0,
                                                const u16* __restrict__ ya1,
                                                const float* __restrict__ ys,
                                                const float* __restrict__ g2,
                                                const float* __restrict__ b2,
                                                float* __restrict__ out,
                                                u16* __restrict__ x2n) {
    int row = blockIdx.x, t = threadIdx.x;
    float4 xv = ((const float4*)(x + (size_t)row * DD))[t];
    uint2 gw = *(const uint2*)(QKVG + (size_t)row * 4096 + 3072 + 4 * t);
    uint2 a0 = *(const uint2*)(ya0 + (size_t)row * DD + 4 * t);
    uint2 a1 = *(const uint2*)(ya1 + (size_t)row * DD + 4 * t);
    float4 sv = ((const float4*)(ys + (size_t)row * DD))[t];
    u16 gh[4] = {(u16)(gw.x & 0xffff), (u16)(gw.x >> 16), (u16)(gw.y & 0xffff), (u16)(gw.y >> 16)};
    u16 ah[4] = {(u16)(a0.x & 0xffff), (u16)(a0.x >> 16), (u16)(a0.y & 0xffff), (u16)(a0.y >> 16)};
    u16 bh[4] = {(u16)(a1.x & 0xffff), (u16)(a1.x >> 16), (u16)(a1.y & 0xffff), (u16)(a1.y >> 16)};
    float xe[4] = {xv.x, xv.y, xv.z, xv.w};
    float se[4] = {sv.x, sv.y, sv.z, sv.w};
    float o[4];
    #pragma unroll
    for (int e = 0; e < 4; e++) {
        float g = 1.0f / (1.0f + __expf(-bf2f(gh[e])));
        float a = bf2f(ah[e]) + bf2f(bh[e]);
        o[e] = xe[e] + g * a + (1.0f - g) * se[e];
    }
    float s = o[0] + o[1] + o[2] + o[3];
    float s2 = o[0]*o[0] + o[1]*o[1] + o[2]*o[2] + o[3]*o[3];
    #pragma unroll
    for (int off = 32; off > 0; off >>= 1) { s += __shfl_xor(s, off); s2 += __shfl_xor(s2, off); }
    __shared__ float red[2][4];
    int wid = t >> 6, lane = t & 63;
    if (lane == 0) { red[0][wid] = s; red[1][wid] = s2; }
    __syncthreads();
    s  = red[0][0] + red[0][1] + red[0][2] + red[0][3];
    s2 = red[1][0] + red[1][1] + red[1][2] + red[1][3];
    float mean = s * (1.0f / DD);
    float var  = s2 * (1.0f / DD) - mean * mean;
    float inv  = rsqrtf(var + 1e-5f);
    float4 gg = ((const float4*)g2)[t];
    float4 bb = ((const float4*)b2)[t];
    float ge[4] = {gg.x, gg.y, gg.z, gg.w};
    float be[4] = {bb.x, bb.y, bb.z, bb.w};
    float4 ov = {o[0], o[1], o[2], o[3]};
    ((float4*)(out + (size_t)row * DD))[t] = ov;
    u16 nh[4];
    #pragma unroll
    for (int e = 0; e < 4; e++) nh[e] = f2bf((o[e] - mean) * inv * ge[e] + be[e]);
    uint2 packed;
    packed.x = (unsigned)nh[0] | ((unsigned)nh[1] << 16);
    packed.y = (unsigned)nh[2] | ((unsigned)nh[3] << 16);
    *(uint2*)(x2n + (size_t)row * DD + 4 * t) = packed;
}

// ---------------- MLP2 partial reduce: out += sum(partials) + b2 ----------------
__global__ __launch_bounds__(256) void mlp2_reduce(const u16* __restrict__ pbase,
                                                   const float* __restrict__ b2,
                                                   float* __restrict__ out) {
    size_t i4 = (size_t)blockIdx.x * 256 + threadIdx.x;  // float4 index
    float4 o = ((float4*)out)[i4];
    float4 bb = ((const float4*)b2)[i4 & 255];
    float acc0 = bb.x, acc1 = bb.y, acc2 = bb.z, acc3 = bb.w;
    #pragma unroll
    for (int z = 0; z < 4; z++) {
        uint2 p = ((const uint2*)(pbase + (size_t)z * ROWSZ))[i4];
        acc0 += bf2f((u16)(p.x & 0xffff));
        acc1 += bf2f((u16)(p.x >> 16));
        acc2 += bf2f((u16)(p.y & 0xffff));
        acc3 += bf2f((u16)(p.y >> 16));
    }
    o.x += acc0; o.y += acc1; o.z += acc2; o.w += acc3;
    ((float4*)out)[i4] = o;
}

extern "C" void kernel_launch(void* const* d_in, const int* in_sizes, int n_in,
                              void* d_out, int out_size, void* d_ws, size_t ws_size,
                              hipStream_t stream) {
    const float* x     = (const float*)d_in[0];
    const float* sst   = (const float*)d_in[1];
    const float* ln1g  = (const float*)d_in[2];
    const float* ln1b  = (const float*)d_in[3];
    const float* ln2g  = (const float*)d_in[4];
    const float* ln2b  = (const float*)d_in[5];
    const float* wq    = (const float*)d_in[6];
    const float* bq    = (const float*)d_in[7];
    const float* wk    = (const float*)d_in[8];
    const float* bk    = (const float*)d_in[9];
    const float* wv    = (const float*)d_in[10];
    const float* bv    = (const float*)d_in[11];
    const float* wo    = (const float*)d_in[12];
    const float* bo    = (const float*)d_in[13];
    const float* wg    = (const float*)d_in[14];
    const float* bg    = (const float*)d_in[15];
    const float* A     = (const float*)d_in[16];
    const float* Bw    = (const float*)d_in[17];
    const float* Cw    = (const float*)d_in[18];
    const float* w1    = (const float*)d_in[19];
    const float* b1    = (const float*)d_in[20];
    const float* w2    = (const float*)d_in[21];
    const float* b2    = (const float*)d_in[22];

    float* out = (float*)d_out;
    char* ws = (char*)d_ws;
    const size_t KBs = 1024;

    u16*   QKVG   = (u16*)(ws);                      // 32 MB [0, 32768K)
    u16*   ya0b   = (u16*)(ws + 34816 * KBs);        //  8 MB
    u16*   ya1b   = (u16*)(ws + 43008 * KBs);        //  8 MB
    float* ys     = (float*)(ws + 51200 * KBs);      // 16 MB
    u16*   uparts = ya0b;                            //  8 MB alias (dead before proj3)
    u16*   parts  = ya0b;                            // 32 MB alias for MLP2 partials
    u16*   xn     = (u16*)(ws + 67584 * KBs);        //  8 MB  (x2n + ubuf alias)
    u16*   ao     = (u16*)(ws + 75776 * KBs);        //  8 MB
    u16*   states = (u16*)(ws + 83968 * KBs);        //  2 MB
    u16*   wqkvgut= (u16*)(ws + 86016 * KBs);        // 8.5 MB (QKVG wts + Bw^T)
    u16*   wot    = (u16*)(ws + 94720 * KBs);        //  2 MB
    u16*   cwt    = (u16*)(ws + 96768 * KBs);        // .5 MB
    u16*   w1t    = (u16*)(ws + 97280 * KBs);        //  8 MB
    u16*   w2t    = (u16*)(ws + 105472 * KBs);       //  8 MB
    float* biasq  = (float*)(ws + 113664 * KBs);     // 16 KB
    u16*   x2n    = xn;       // xn dead after QKVG+u gemms
    u16*   ubuf   = xn;       // 2 MB; consumed by attn_scan before x2n write
    u16*   h1     = QKVG;     // QKVG dead after fuse_ln2

    float* new_state_out = out + ROWSZ;

    // 0. weight transposes + bias concat
    hipLaunchKernelGGL(tconv_all, dim3(13824), dim3(256), 0, stream,
                       wq, wk, wv, wg, Bw, wo, Cw, w1, w2,
                       wqkvgut, wot, cwt, w1t, w2t);
    hipLaunchKernelGGL(bias_init, dim3(16), dim3(256), 0, stream, bq, bk, bv, bg, biasq);

    // 1. LN1 -> bf16
    hipLaunchKernelGGL(ln_kernel, dim3(ROWS), dim3(256), 0, stream, x, ln1g, ln1b, xn);
    // 2. QKVG projection (N=4096): 16x16 = 256 blocks (1/CU, perfect fill)
    hipLaunchKernelGGL((mgemm64<0,true,false>), dim3(256, 1), dim3(512), 0, stream,
                       xn, wqkvgut, biasq, (void*)QKVG, ROWS, 4096, 1024, 1024,
                       16, 16, 4, 2);
    // 3. u = xn @ Bw: K-split 4 (Kslice=256, kiters=4) -> 16x4 = 64 blocks
    hipLaunchKernelGGL((mgemm64<0,true,true>), dim3(16, 4), dim3(512), 0, stream,
                       xn, wqkvgut + (size_t)4096 * 1024, (const float*)nullptr,
                       (void*)uparts, ROWS, 256, 1024, 256,
                       16, 1, 8, 1);
    // 4. u partial reduce -> ubuf bf16
    hipLaunchKernelGGL(ureduce, dim3(1024), dim3(256), 0, stream, uparts, ubuf);
    // 5. MFMA attention + chunked SSM scan, one launch
    hipLaunchKernelGGL(attn_scan, dim3(1088), dim3(256), 0, stream,
                       QKVG, ubuf, ao, A, sst, states, new_state_out);
    // 6. fused wo (split-2, bf16 partials) + cw projection, one launch
    hipLaunchKernelGGL(proj3, dim3(4, 16, 3), dim3(512), 0, stream,
                       ao, states, wot, cwt, bo, ya0b, ya1b, ys);
    // 7. gate/residual + LN2 fused -> out fp32, x2n bf16
    hipLaunchKernelGGL(fuse_ln2, dim3(ROWS), dim3(256), 0, stream,
                       x, QKVG, ya0b, ya1b, ys, ln2g, ln2b, out, x2n);
    // 8. h1 = gelu(x2n @ w1 + b1) -> bf16; 256 blocks
    hipLaunchKernelGGL((mgemm64<1,true,false>), dim3(256, 1), dim3(512), 0, stream,
                       x2n, w1t, b1, (void*)h1, ROWS, 4*DD, 1024, 1024,
                       16, 16, 4, 2);
    // 9. MLP2 split-4 -> bf16 partials; 64x4 = 256 blocks
    hipLaunchKernelGGL((mgemm64<0,true,true>), dim3(64, 4), dim3(512), 0, stream,
                       h1, w2t, (const float*)nullptr, (void*)parts, ROWS, DD, 4096, 1024,
                       16, 4, 8, 1);
    // 10. out += sum(partials) + b2
    hipLaunchKernelGGL(mlp2_reduce, dim3(4096), dim3(256), 0, stream, parts, b2, out);
}

// Round 8
// 394.604 us; speedup vs baseline: 2.7008x; 2.7008x over previous
//
#include <hip/hip_runtime.h>
#include <math.h>

#define BB 2
#define TT 2048
#define DD 1024
#define HH 16
#define DH 64
#define WW 256
#define NN 256
#define ROWS (BB*TT)             // 4096
#define ROWSZ ((size_t)ROWS*DD)  // 4,194,304

typedef unsigned short u16;
typedef __attribute__((ext_vector_type(8))) short short8;
typedef __attribute__((ext_vector_type(4))) float f32x4;

__device__ __forceinline__ float bf2f(u16 h) {
    union { unsigned int u; float f; } c; c.u = ((unsigned int)h) << 16; return c.f;
}
__device__ __forceinline__ u16 f2bf(float f) {
    union { float f; unsigned int u; } c; c.f = f;
    unsigned int r = c.u + 0x7fffu + ((c.u >> 16) & 1u);
    return (u16)(r >> 16);
}

__device__ __forceinline__ void gld16(const void* g, void* l) {
    __builtin_amdgcn_global_load_lds(
        (const __attribute__((address_space(1))) void*)g,
        (__attribute__((address_space(3))) void*)l, 16, 0, 0);
}

// ---------------- LayerNorm (fp32 in -> bf16 out) ----------------
__global__ __launch_bounds__(256) void ln_kernel(const float* __restrict__ x,
                                                 const float* __restrict__ g,
                                                 const float* __restrict__ b,
                                                 u16* __restrict__ out) {
    int row = blockIdx.x;
    int t = threadIdx.x;
    const float4* xr = (const float4*)(x + (size_t)row * DD);
    float4 v4 = xr[t];
    float s  = v4.x + v4.y + v4.z + v4.w;
    float s2 = v4.x*v4.x + v4.y*v4.y + v4.z*v4.z + v4.w*v4.w;
    #pragma unroll
    for (int o = 32; o > 0; o >>= 1) { s += __shfl_xor(s, o); s2 += __shfl_xor(s2, o); }
    __shared__ float red[2][4];
    int wid = t >> 6, lane = t & 63;
    if (lane == 0) { red[0][wid] = s; red[1][wid] = s2; }
    __syncthreads();
    s  = red[0][0] + red[0][1] + red[0][2] + red[0][3];
    s2 = red[1][0] + red[1][1] + red[1][2] + red[1][3];
    float mean = s * (1.0f / DD);
    float var  = s2 * (1.0f / DD) - mean * mean;
    float inv  = rsqrtf(var + 1e-5f);
    const float4* g4 = (const float4*)g;
    const float4* b4 = (const float4*)b;
    float4 gg = g4[t], bb = b4[t];
    float o0 = (v4.x - mean) * inv * gg.x + bb.x;
    float o1 = (v4.y - mean) * inv * gg.y + bb.y;
    float o2 = (v4.z - mean) * inv * gg.z + bb.z;
    float o3 = (v4.w - mean) * inv * gg.w + bb.w;
    uint2 packed;
    packed.x = (unsigned)f2bf(o0) | ((unsigned)f2bf(o1) << 16);
    packed.y = (unsigned)f2bf(o2) | ((unsigned)f2bf(o3) << 16);
    *(uint2*)(out + (size_t)row * DD + 4 * t) = packed;
}

// ---------------- all weight transpose-converts in ONE launch ----------------
__global__ __launch_bounds__(256) void tconv_all(
    const float* __restrict__ wq, const float* __restrict__ wk,
    const float* __restrict__ wv, const float* __restrict__ wg,
    const float* __restrict__ Bw, const float* __restrict__ wo,
    const float* __restrict__ Cw, const float* __restrict__ w1,
    const float* __restrict__ w2,
    u16* __restrict__ wqkvgut, u16* __restrict__ wot, u16* __restrict__ cwt,
    u16* __restrict__ w1t, u16* __restrict__ w2t) {
    int tile = blockIdx.x;
    const float* src; u16* dst; int K, N, tx, ty;
    if (tile < 4096) {
        int seg = tile >> 10, tl = tile & 1023;
        src = (seg == 0) ? wq : (seg == 1) ? wk : (seg == 2) ? wv : wg;
        dst = wqkvgut + (size_t)seg * 1024 * 1024;
        K = 1024; N = 1024; tx = tl & 31; ty = tl >> 5;
    } else if (tile < 4352) {
        int tl = tile - 4096;
        src = Bw; dst = wqkvgut + (size_t)4096 * 1024;
        K = 1024; N = 256; tx = tl & 7; ty = tl >> 3;
    } else if (tile < 5376) {
        int tl = tile - 4352;
        src = wo; dst = wot; K = 1024; N = 1024; tx = tl & 31; ty = tl >> 5;
    } else if (tile < 5632) {
        int tl = tile - 5376;
        src = Cw; dst = cwt; K = 256; N = 1024; tx = tl & 31; ty = tl >> 5;
    } else if (tile < 9728) {
        int tl = tile - 5632;
        src = w1; dst = w1t; K = 1024; N = 4096; tx = tl & 127; ty = tl >> 7;
    } else {
        int tl = tile - 9728;
        src = w2; dst = w2t; K = 4096; N = 1024; tx = tl & 31; ty = tl >> 5;
    }
    __shared__ float ts[32][33];
    int n0 = tx * 32, k0 = ty * 32;
    int tc = threadIdx.x & 31, tr = threadIdx.x >> 5;
    #pragma unroll
    for (int i = tr; i < 32; i += 8)
        ts[i][tc] = src[(size_t)(k0 + i) * N + n0 + tc];
    __syncthreads();
    #pragma unroll
    for (int i = tr; i < 32; i += 8)
        dst[(size_t)(n0 + i) * K + k0 + tc] = f2bf(ts[tc][i]);
}

// ---------------- bias concat for fused QKVG gemm ----------------
__global__ __launch_bounds__(256) void bias_init(const float* __restrict__ bq,
                                                 const float* __restrict__ bk,
                                                 const float* __restrict__ bv,
                                                 const float* __restrict__ bg,
                                                 float* __restrict__ dst) {
    int i = blockIdx.x * 256 + threadIdx.x;
    if (i >= 4096) return;
    float v;
    if (i < 1024) v = bq[i];
    else if (i < 2048) v = bk[i - 1024];
    else if (i < 3072) v = bv[i - 2048];
    else v = bg[i - 3072];
    dst[i] = v;
}

// ============ 8-phase counted-vmcnt 256x256 MFMA GEMM core (BK=64) ============
// EXACT core that benched in R3: VGPR 104, 0 spill, 0 bank conflicts,
// 929 TF in-round (74us/272-block grid = 2 rounds; tail was the loss, not
// the core). This round only the LAUNCH GRIDS change (perfect 256-block
// fills); the core is byte-identical.
// 512 threads = 8 waves (2M x 4N). Per-wave output 128x64 = acc[8][4] f32x4.
// LDS: 2 buffers x (A 256x64 + B 256x64) bf16 = 128 KiB. 4 phases per K-tile;
// each phase: ds_read A-chunk (+all B at ph0), issue 2 stage chunks of tile
// kt+1, counted s_waitcnt vmcnt(N), s_barrier, setprio(1), 16 MFMA,
// setprio(0), s_barrier. Stage chunk = 64 rows x 64 k = 1 gld16/thread.
// Issue order per tile: B0,B1 | B2,B3 | A0,A1 | A2,A3.
// Steady waits: ph0 vmcnt(4), ph1 vmcnt(5), ph2 vmcnt(6), ph3 vmcnt(3);
// last tile: 2/1/0/-. vmcnt never drains to 0 in the steady loop (T4).
// XOR chunk swizzle (T2): row of 128B = 8 chunks of 16B; chunk j of row r
// stored at pos p = j ^ (r&7); stage source pre-swizzled, reads use
// csw = (kchunk ^ (rq&7))<<4 -> 2 words/bank (free).
#define TILEB 32768

__device__ __forceinline__ void gemm_core_8ph(const u16* __restrict__ A,
                                              const u16* __restrict__ Bt,
                                              int K, int kiters, int kofs,
                                              int m0, int n0,
                                              char* Als, char* Bls,
                                              int t, f32x4 acc[8][4]) {
    int lane = t & 63, wid = t >> 6;
    int wm = wid >> 2, wn = wid & 3;
    int jq = lane >> 4, rq = lane & 15;
    int csw0 = (jq ^ (rq & 7)) << 4;
    int csw1 = ((4 + jq) ^ (rq & 7)) << 4;
    int rowB[4];
    #pragma unroll
    for (int jn = 0; jn < 4; jn++) rowB[jn] = (wn * 64 + jn * 16 + rq) * 128;
    int rowA[8];
    #pragma unroll
    for (int i = 0; i < 8; i++) rowA[i] = (i * 32 + wm * 16 + rq) * 128;

    // staging: one 16B slot per thread per 64-row chunk
    int r0 = t >> 3, p8 = t & 7;
    int jg = p8 ^ (r0 & 7);
    const char* gAb = (const char*)(A + (size_t)(m0 + r0) * K + kofs) + jg * 16;
    const char* gBb = (const char*)(Bt + (size_t)(n0 + r0) * K + kofs) + jg * 16;
    size_t st64 = (size_t)K * 128;   // 64 rows * K * 2B
    int ldst = t * 16;

    // prologue: full stage of tile 0 -> buf0, drain
    #pragma unroll
    for (int q = 0; q < 4; q++) gld16(gBb + q * st64, Bls + q * 8192 + ldst);
    #pragma unroll
    for (int q = 0; q < 4; q++) gld16(gAb + q * st64, Als + q * 8192 + ldst);
    asm volatile("s_waitcnt vmcnt(0)" ::: "memory");
    __builtin_amdgcn_s_barrier();

    short8 bfr[4][2];

#define MFMA_SET(P) \
    __builtin_amdgcn_s_setprio(1); \
    _Pragma("unroll") \
    for (int ii = 0; ii < 2; ii++) { \
        _Pragma("unroll") \
        for (int jn = 0; jn < 4; jn++) { \
            acc[2*(P)+ii][jn] = __builtin_amdgcn_mfma_f32_16x16x32_bf16(af[ii][0], bfr[jn][0], acc[2*(P)+ii][jn], 0, 0, 0); \
            acc[2*(P)+ii][jn] = __builtin_amdgcn_mfma_f32_16x16x32_bf16(af[ii][1], bfr[jn][1], acc[2*(P)+ii][jn], 0, 0, 0); \
        } \
    } \
    __builtin_amdgcn_s_setprio(0); \
    __builtin_amdgcn_s_barrier();

    for (int kt = 0; kt < kiters; kt++) {
        int cur = kt & 1, nxt = cur ^ 1;
        bool nl = (kt + 1 < kiters);
        size_t kn = (size_t)(kt + 1) * 128;
        const char* Ab = Als + cur * TILEB;
        const char* Bb = Bls + cur * TILEB;
        char* An = Als + nxt * TILEB;
        char* Bn = Bls + nxt * TILEB;

        { // phase 0: A-chunk0 reads + all B reads; stage B0,B1(next)
            short8 af[2][2];
            #pragma unroll
            for (int ii = 0; ii < 2; ii++) {
                af[ii][0] = *(const short8*)(Ab + rowA[ii] + csw0);
                af[ii][1] = *(const short8*)(Ab + rowA[ii] + csw1);
            }
            #pragma unroll
            for (int jn = 0; jn < 4; jn++) {
                bfr[jn][0] = *(const short8*)(Bb + rowB[jn] + csw0);
                bfr[jn][1] = *(const short8*)(Bb + rowB[jn] + csw1);
            }
            if (nl) {
                gld16(gBb + kn, Bn + ldst);
                gld16(gBb + kn + st64, Bn + 8192 + ldst);
                asm volatile("s_waitcnt vmcnt(4)" ::: "memory");
            } else {
                asm volatile("s_waitcnt vmcnt(2)" ::: "memory");
            }
            __builtin_amdgcn_s_barrier();
            MFMA_SET(0)
        }
        { // phase 1: A-chunk1; stage B2,B3(next)
            short8 af[2][2];
            #pragma unroll
            for (int ii = 0; ii < 2; ii++) {
                af[ii][0] = *(const short8*)(Ab + rowA[2+ii] + csw0);
                af[ii][1] = *(const short8*)(Ab + rowA[2+ii] + csw1);
            }
            if (nl) {
                gld16(gBb + kn + 2*st64, Bn + 2*8192 + ldst);
                gld16(gBb + kn + 3*st64, Bn + 3*8192 + ldst);
                asm volatile("s_waitcnt vmcnt(5)" ::: "memory");
            } else {
                asm volatile("s_waitcnt vmcnt(1)" ::: "memory");
            }
            __builtin_amdgcn_s_barrier();
            MFMA_SET(1)
        }
        { // phase 2: A-chunk2; stage A0,A1(next)
            short8 af[2][2];
            #pragma unroll
            for (int ii = 0; ii < 2; ii++) {
                af[ii][0] = *(const short8*)(Ab + rowA[4+ii] + csw0);
                af[ii][1] = *(const short8*)(Ab + rowA[4+ii] + csw1);
            }
            if (nl) {
                gld16(gAb + kn, An + ldst);
                gld16(gAb + kn + st64, An + 8192 + ldst);
                asm volatile("s_waitcnt vmcnt(6)" ::: "memory");
            } else {
                asm volatile("s_waitcnt vmcnt(0)" ::: "memory");
            }
            __builtin_amdgcn_s_barrier();
            MFMA_SET(2)
        }
        { // phase 3: A-chunk3; stage A2,A3(next)
            short8 af[2][2];
            #pragma unroll
            for (int ii = 0; ii < 2; ii++) {
                af[ii][0] = *(const short8*)(Ab + rowA[6+ii] + csw0);
                af[ii][1] = *(const short8*)(Ab + rowA[6+ii] + csw1);
            }
            if (nl) {
                gld16(gAb + kn + 2*st64, An + 2*8192 + ldst);
                gld16(gAb + kn + 3*st64, An + 3*8192 + ldst);
                asm volatile("s_waitcnt vmcnt(3)" ::: "memory");
            }
            __builtin_amdgcn_s_barrier();
            MFMA_SET(3)
        }
    }
#undef MFMA_SET
}

// ---------------- generic 256^2 GEMM kernel (XCD-swizzled 1-D grid) ----------------
template<int ACT, bool OUTBF, bool SPLIT>
__global__ __launch_bounds__(512, 2) void mgemm64(const u16* __restrict__ A,
                                                  const u16* __restrict__ Bt,
                                                  const float* __restrict__ bias,
                                                  void* __restrict__ C,
                                                  int M, int N, int K, int Kslice,
                                                  int mtiles, int ntiles, int PM, int PN) {
    __shared__ __align__(16) char Als[2 * TILEB];
    __shared__ __align__(16) char Bls[2 * TILEB];
    int t = threadIdx.x;
    int l = blockIdx.x;
    int xcd = l & 7, li = l >> 3;
    int rm = mtiles / PM, rn = ntiles / PN;
    int xm = xcd % PM, xn = xcd / PM;
    int mt = xm * rm + li % rm;
    int nt = xn * rn + li / rm;
    int m0 = mt * 256, n0 = nt * 256;
    int z = SPLIT ? blockIdx.y : 0;
    f32x4 acc[8][4];
    #pragma unroll
    for (int i = 0; i < 8; i++)
        #pragma unroll
        for (int j = 0; j < 4; j++)
            acc[i][j] = (f32x4){0.f, 0.f, 0.f, 0.f};
    gemm_core_8ph(A, Bt, K, Kslice >> 6, z * Kslice, m0, n0, Als, Bls, t, acc);

    int lane = t & 63, wid = t >> 6;
    int wm = wid >> 2, wn = wid & 3;
    int jq = lane >> 4, rq = lane & 15;
    u16* Cb = OUTBF ? ((u16*)C + (SPLIT ? (size_t)z * M * N : (size_t)0)) : nullptr;
    float* Cf = (float*)C;
    #pragma unroll
    for (int i = 0; i < 8; i++) {
        int rowb = m0 + i * 32 + wm * 16 + jq * 4;
        #pragma unroll
        for (int jn = 0; jn < 4; jn++) {
            int col = n0 + wn * 64 + jn * 16 + rq;
            float bv = bias ? bias[col] : 0.f;
            #pragma unroll
            for (int rr = 0; rr < 4; rr++) {
                float v = acc[i][jn][rr] + bv;
                if (ACT == 1) v = 0.5f * v * (1.0f + erff(v * 0.70710678118654752f));
                size_t off = (size_t)(rowb + rr) * N + col;
                if (OUTBF) Cb[off] = f2bf(v);
                else Cf[off] = v;
            }
        }
    }
}

// ---------------- u partial reduce: u = sum_z(parts[z]) (bf16) ----------------
__global__ __launch_bounds__(256) void ureduce(const u16* __restrict__ p,
                                               u16* __restrict__ o) {
    size_t i2 = (size_t)blockIdx.x * 256 + threadIdx.x;  // uint2 = 4 bf16
    float a0 = 0.f, a1 = 0.f, a2 = 0.f, a3 = 0.f;
    #pragma unroll
    for (int z = 0; z < 4; z++) {
        uint2 v = ((const uint2*)(p + (size_t)z * 1048576))[i2];
        a0 += bf2f((u16)(v.x & 0xffff));
        a1 += bf2f((u16)(v.x >> 16));
        a2 += bf2f((u16)(v.y & 0xffff));
        a3 += bf2f((u16)(v.y >> 16));
    }
    uint2 r;
    r.x = (unsigned)f2bf(a0) | ((unsigned)f2bf(a1) << 16);
    r.y = (unsigned)f2bf(a2) | ((unsigned)f2bf(a3) << 16);
    ((uint2*)o)[i2] = r;
}

// ---------------- fused wo + cw projection (grid.z selects job) ----------------
__global__ __launch_bounds__(512, 2) void proj3(const u16* __restrict__ ao,
                                                const u16* __restrict__ states,
                                                const u16* __restrict__ wot,
                                                const u16* __restrict__ cwt,
                                                const float* __restrict__ bo,
                                                u16* __restrict__ ya0,
                                                u16* __restrict__ ya1,
                                                float* __restrict__ ys) {
    __shared__ __align__(16) char Als[2 * TILEB];
    __shared__ __align__(16) char Bls[2 * TILEB];
    int t = threadIdx.x;
    int m0 = blockIdx.y * 256, n0 = blockIdx.x * 256;
    int z = blockIdx.z;
    const u16* A; const u16* Bt; int K, kofs, kiters;
    if (z < 2) { A = ao; Bt = wot; K = 1024; kofs = z * 512; kiters = 8; }
    else       { A = states; Bt = cwt; K = 256; kofs = 0; kiters = 4; }
    f32x4 acc[8][4];
    #pragma unroll
    for (int i = 0; i < 8; i++)
        #pragma unroll
        for (int j = 0; j < 4; j++)
            acc[i][j] = (f32x4){0.f, 0.f, 0.f, 0.f};
    gemm_core_8ph(A, Bt, K, kiters, kofs, m0, n0, Als, Bls, t, acc);

    int lane = t & 63, wid = t >> 6;
    int wm = wid >> 2, wn = wid & 3;
    int jq = lane >> 4, rq = lane & 15;
    u16* dst = (z == 0) ? ya0 : ya1;
    #pragma unroll
    for (int i = 0; i < 8; i++) {
        int rowb = m0 + i * 32 + wm * 16 + jq * 4;
        #pragma unroll
        for (int jn = 0; jn < 4; jn++) {
            int col = n0 + wn * 64 + jn * 16 + rq;
            float bv = (z == 0) ? bo[col] : 0.f;
            #pragma unroll
            for (int rr = 0; rr < 4; rr++) {
                float v = acc[i][jn][rr] + bv;
                size_t off = (size_t)(rowb + rr) * DD + col;
                if (z < 2) dst[off] = f2bf(v);
                else ys[off] = v;
            }
        }
    }
}

// ---------------- MFMA sliding-window attention + SSM scan (merged launch) ----------------
// QKVG rows are 4096 wide (Q|K|V|G); u is a separate [ROWS][256] bf16 buffer.
__global__ __launch_bounds__(256) void attn_scan(const u16* __restrict__ QKVG,
                                                 const u16* __restrict__ ubuf,
                                                 u16* __restrict__ O,
                                                 const float* __restrict__ Assm,
                                                 const float* __restrict__ s0,
                                                 u16* __restrict__ states,
                                                 float* __restrict__ s_out) {
    __shared__ __align__(16) short Qs[8][64][8];
    __shared__ __align__(16) short Ks[8][64][8];
    __shared__ __align__(16) short Vt[64][72];
    __shared__ __align__(16) short Ps[4][16][72];

    if (blockIdx.x >= 1024) {
        int idx = (blockIdx.x - 1024) * 256 + threadIdx.x;
        int n = idx & 255;
        int c = (idx >> 8) & 31;
        int b = idx >> 13;
        float alpha = tanhf(Assm[n]);
        int t0 = c * 64;
        float s = (c == 0) ? s0[b * NN + n] : 0.f;
        const u16* up = ubuf + (size_t)(b * TT) * NN + n;
        if (c > 0) {
            #pragma unroll
            for (int k = 8; k >= 1; k--)
                s = alpha * s + bf2f(up[(size_t)(t0 - k) * NN]);
        }
        u16* sp = states + (size_t)(b * TT) * NN + n;
        for (int t = t0; t < t0 + 64; t++) {
            s = alpha * s + bf2f(up[(size_t)t * NN]);
            sp[(size_t)t * NN] = f2bf(s);
        }
        if (c == 31) s_out[b * NN + n] = s;
        return;
    }

    int blk = blockIdx.x;
    int qb = blk & 31;
    int h  = (blk >> 5) & 15;
    int b  = blk >> 9;
    int q0 = qb * 64;
    int t = threadIdx.x, lane = t & 63, w = t >> 6;
    int rq = lane & 15, jq = lane >> 4;

    const size_t RS = 4096;

    #pragma unroll
    for (int i = 0; i < 2; i++) {
        int c = 2 * w + i;
        const u16* g = QKVG + (size_t)(b * TT + q0 + lane) * RS + h * 64 + c * 8;
        gld16(g, (char*)Qs + c * 1024);
    }

    f32x4 Oa[4];
    #pragma unroll
    for (int tj = 0; tj < 4; tj++) Oa[tj] = (f32x4){0.f, 0.f, 0.f, 0.f};
    float mrow[4], lrow[4];
    #pragma unroll
    for (int r = 0; r < 4; r++) { mrow[r] = -1e30f; lrow[r] = 0.f; }

    int c0 = 4 - (q0 >> 6); if (c0 < 0) c0 = 0;

    for (int ci = c0; ci < 5; ci++) {
        int kbase = q0 - 256 + ci * 64;
        #pragma unroll
        for (int i = 0; i < 2; i++) {
            int c = 2 * w + i;
            const u16* g = QKVG + (size_t)(b * TT + kbase + lane) * RS + 1024 + h * 64 + c * 8;
            gld16(g, (char*)Ks + c * 1024);
        }
        #pragma unroll
        for (int i = 0; i < 2; i++) {
            int dhg = i * 4 + w;
            uint4 v = *(const uint4*)(QKVG + (size_t)(b * TT + kbase + lane) * RS + 2048 + h * 64 + dhg * 8);
            const u16* pv = (const u16*)&v;
            #pragma unroll
            for (int j = 0; j < 8; j++) Vt[dhg * 8 + j][lane] = (short)pv[j];
        }
        __syncthreads();

        short8 qf[2];
        #pragma unroll
        for (int s = 0; s < 2; s++)
            qf[s] = *(const short8*)&Qs[4 * s + jq][w * 16 + rq][0];

        f32x4 S[4];
        #pragma unroll
        for (int tj = 0; tj < 4; tj++) S[tj] = (f32x4){0.f, 0.f, 0.f, 0.f};
        #pragma unroll
        for (int s = 0; s < 2; s++)
            #pragma unroll
            for (int tj = 0; tj < 4; tj++) {
                short8 kf = *(const short8*)&Ks[4 * s + jq][tj * 16 + rq][0];
                S[tj] = __builtin_amdgcn_mfma_f32_16x16x32_bf16(qf[s], kf, S[tj], 0, 0, 0);
            }

        #pragma unroll
        for (int r = 0; r < 4; r++) {
            int q = q0 + w * 16 + jq * 4 + r;
            float sv[4];
            #pragma unroll
            for (int tj = 0; tj < 4; tj++) {
                int kp = kbase + tj * 16 + rq;
                float x = S[tj][r] * 0.125f;
                bool valid = (kp <= q) && (kp > q - WW);
                sv[tj] = valid ? x : -1e30f;
            }
            float cm = fmaxf(fmaxf(sv[0], sv[1]), fmaxf(sv[2], sv[3]));
            #pragma unroll
            for (int o = 1; o < 16; o <<= 1) cm = fmaxf(cm, __shfl_xor(cm, o));
            float mn = fmaxf(mrow[r], cm);
            bool any = mn > -1e29f;
            float al = any ? __expf(mrow[r] - mn) : 1.f;
            float ps = 0.f;
            #pragma unroll
            for (int tj = 0; tj < 4; tj++) {
                float p = any ? __expf(sv[tj] - mn) : 0.f;
                ps += p;
                Ps[w][jq * 4 + r][tj * 16 + rq] = (short)f2bf(p);
            }
            #pragma unroll
            for (int o = 1; o < 16; o <<= 1) ps += __shfl_xor(ps, o);
            lrow[r] = lrow[r] * al + ps;
            mrow[r] = mn;
            #pragma unroll
            for (int tj = 0; tj < 4; tj++) Oa[tj][r] *= al;
        }

        #pragma unroll
        for (int s = 0; s < 2; s++) {
            short8 pf = *(const short8*)&Ps[w][rq][32 * s + 8 * jq];
            #pragma unroll
            for (int tj = 0; tj < 4; tj++) {
                short8 vf = *(const short8*)&Vt[tj * 16 + rq][32 * s + 8 * jq];
                Oa[tj] = __builtin_amdgcn_mfma_f32_16x16x32_bf16(pf, vf, Oa[tj], 0, 0, 0);
            }
        }
        __syncthreads();
    }

    #pragma unroll
    for (int r = 0; r < 4; r++) {
        int q = q0 + w * 16 + jq * 4 + r;
        float inv = 1.f / lrow[r];
        #pragma unroll
        for (int tj = 0; tj < 4; tj++)
            O[(size_t)(b * TT + q) * DD + h * 64 + tj * 16 + rq] = f2bf(Oa[tj][r] * inv);
    }
}

// ---------------- fused gate/residual + LayerNorm2 ----------------
__global__ __launch_bounds__(256) void fuse_ln2(const float* __restrict__ x,
                                                const u16* __restrict__ QKVG,
                                                const u16* __restrict__ ya0,
                                                const u16* __restrict__ ya1,
                                                const float* __restrict__ ys,
                                                const float* __restrict__ g2,
                                                const float* __restrict__ b2,
                                                float* __restrict__ out,
                                                u16* __restrict__ x2n) {
    int row = blockIdx.x, t = threadIdx.x;
    float4 xv = ((const float4*)(x + (size_t)row * DD))[t];
    uint2 gw = *(const uint2*)(QKVG + (size_t)row * 4096 + 3072 + 4 * t);
    uint2 a0 = *(const uint2*)(ya0 + (size_t)row * DD + 4 * t);
    uint2 a1 = *(const uint2*)(ya1 + (size_t)row * DD + 4 * t);
    float4 sv = ((const float4*)(ys + (size_t)row * DD))[t];
    u16 gh[4] = {(u16)(gw.x & 0xffff), (u16)(gw.x >> 16), (u16)(gw.y & 0xffff), (u16)(gw.y >> 16)};
    u16 ah[4] = {(u16)(a0.x & 0xffff), (u16)(a0.x >> 16), (u16)(a0.y & 0xffff), (u16)(a0.y >> 16)};
    u16 bh[4] = {(u16)(a1.x & 0xffff), (u16)(a1.x >> 16), (u16)(a1.y & 0xffff), (u16)(a1.y >> 16)};
    float xe[4] = {xv.x, xv.y, xv.z, xv.w};
    float se[4] = {sv.x, sv.y, sv.z, sv.w};
    float o[4];
    #pragma unroll
    for (int e = 0; e < 4; e++) {
        float g = 1.0f / (1.0f + __expf(-bf2f(gh[e])));
        float a = bf2f(ah[e]) + bf2f(bh[e]);
        o[e] = xe[e] + g * a + (1.0f - g) * se[e];
    }
    float s = o[0] + o[1] + o[2] + o[3];
    float s2 = o[0]*o[0] + o[1]*o[1] + o[2]*o[2] + o[3]*o[3];
    #pragma unroll
    for (int off = 32; off > 0; off >>= 1) { s += __shfl_xor(s, off); s2 += __shfl_xor(s2, off); }
    __shared__ float red[2][4];
    int wid = t >> 6, lane = t & 63;
    if (lane == 0) { red[0][wid] = s; red[1][wid] = s2; }
    __syncthreads();
    s  = red[0][0] + red[0][1] + red[0][2] + red[0][3];
    s2 = red[1][0] + red[1][1] + red[1][2] + red[1][3];
    float mean = s * (1.0f / DD);
    float var  = s2 * (1.0f / DD) - mean * mean;
    float inv  = rsqrtf(var + 1e-5f);
    float4 gg = ((const float4*)g2)[t];
    float4 bb = ((const float4*)b2)[t];
    float ge[4] = {gg.x, gg.y, gg.z, gg.w};
    float be[4] = {bb.x, bb.y, bb.z, bb.w};
    float4 ov = {o[0], o[1], o[2], o[3]};
    ((float4*)(out + (size_t)row * DD))[t] = ov;
    u16 nh[4];
    #pragma unroll
    for (int e = 0; e < 4; e++) nh[e] = f2bf((o[e] - mean) * inv * ge[e] + be[e]);
    uint2 packed;
    packed.x = (unsigned)nh[0] | ((unsigned)nh[1] << 16);
    packed.y = (unsigned)nh[2] | ((unsigned)nh[3] << 16);
    *(uint2*)(x2n + (size_t)row * DD + 4 * t) = packed;
}

// ---------------- MLP2 partial reduce: out += sum(partials) + b2 ----------------
__global__ __launch_bounds__(256) void mlp2_reduce(const u16* __restrict__ pbase,
                                                   const float* __restrict__ b2,
                                                   float* __restrict__ out) {
    size_t i4 = (size_t)blockIdx.x * 256 + threadIdx.x;  // float4 index
    float4 o = ((float4*)out)[i4];
    float4 bb = ((const float4*)b2)[i4 & 255];
    float acc0 = bb.x, acc1 = bb.y, acc2 = bb.z, acc3 = bb.w;
    #pragma unroll
    for (int z = 0; z < 4; z++) {
        uint2 p = ((const uint2*)(pbase + (size_t)z * ROWSZ))[i4];
        acc0 += bf2f((u16)(p.x & 0xffff));
        acc1 += bf2f((u16)(p.x >> 16));
        acc2 += bf2f((u16)(p.y & 0xffff));
        acc3 += bf2f((u16)(p.y >> 16));
    }
    o.x += acc0; o.y += acc1; o.z += acc2; o.w += acc3;
    ((float4*)out)[i4] = o;
}

extern "C" void kernel_launch(void* const* d_in, const int* in_sizes, int n_in,
                              void* d_out, int out_size, void* d_ws, size_t ws_size,
                              hipStream_t stream) {
    const float* x     = (const float*)d_in[0];
    const float* sst   = (const float*)d_in[1];
    const float* ln1g  = (const float*)d_in[2];
    const float* ln1b  = (const float*)d_in[3];
    const float* ln2g  = (const float*)d_in[4];
    const float* ln2b  = (const float*)d_in[5];
    const float* wq    = (const float*)d_in[6];
    const float* bq    = (const float*)d_in[7];
    const float* wk    = (const float*)d_in[8];
    const float* bk    = (const float*)d_in[9];
    const float* wv    = (const float*)d_in[10];
    const float* bv    = (const float*)d_in[11];
    const float* wo    = (const float*)d_in[12];
    const float* bo    = (const float*)d_in[13];
    const float* wg    = (const float*)d_in[14];
    const float* bg    = (const float*)d_in[15];
    const float* A     = (const float*)d_in[16];
    const float* Bw    = (const float*)d_in[17];
    const float* Cw    = (const float*)d_in[18];
    const float* w1    = (const float*)d_in[19];
    const float* b1    = (const float*)d_in[20];
    const float* w2    = (const float*)d_in[21];
    const float* b2    = (const float*)d_in[22];

    float* out = (float*)d_out;
    char* ws = (char*)d_ws;
    const size_t KBs = 1024;

    u16*   QKVG   = (u16*)(ws);                      // 32 MB [0, 32768K)
    u16*   ya0b   = (u16*)(ws + 34816 * KBs);        //  8 MB
    u16*   ya1b   = (u16*)(ws + 43008 * KBs);        //  8 MB
    float* ys     = (float*)(ws + 51200 * KBs);      // 16 MB
    u16*   uparts = ya0b;                            //  8 MB alias (dead before proj3)
    u16*   parts  = ya0b;                            // 32 MB alias for MLP2 partials
    u16*   xn     = (u16*)(ws + 67584 * KBs);        //  8 MB  (x2n + ubuf alias)
    u16*   ao     = (u16*)(ws + 75776 * KBs);        //  8 MB
    u16*   states = (u16*)(ws + 83968 * KBs);        //  2 MB
    u16*   wqkvgut= (u16*)(ws + 86016 * KBs);        // 8.5 MB (QKVG wts + Bw^T)
    u16*   wot    = (u16*)(ws + 94720 * KBs);        //  2 MB
    u16*   cwt    = (u16*)(ws + 96768 * KBs);        // .5 MB
    u16*   w1t    = (u16*)(ws + 97280 * KBs);        //  8 MB
    u16*   w2t    = (u16*)(ws + 105472 * KBs);       //  8 MB
    float* biasq  = (float*)(ws + 113664 * KBs);     // 16 KB
    u16*   x2n    = xn;       // xn dead after QKVG+u gemms
    u16*   ubuf   = xn;       // 2 MB; consumed by attn_scan before x2n write
    u16*   h1     = QKVG;     // QKVG dead after fuse_ln2

    float* new_state_out = out + ROWSZ;

    // 0. weight transposes + bias concat
    hipLaunchKernelGGL(tconv_all, dim3(13824), dim3(256), 0, stream,
                       wq, wk, wv, wg, Bw, wo, Cw, w1, w2,
                       wqkvgut, wot, cwt, w1t, w2t);
    hipLaunchKernelGGL(bias_init, dim3(16), dim3(256), 0, stream, bq, bk, bv, bg, biasq);

    // 1. LN1 -> bf16
    hipLaunchKernelGGL(ln_kernel, dim3(ROWS), dim3(256), 0, stream, x, ln1g, ln1b, xn);
    // 2. QKVG projection (N=4096): 16x16 = 256 blocks (1/CU, perfect 1-round fill)
    hipLaunchKernelGGL((mgemm64<0,true,false>), dim3(256, 1), dim3(512), 0, stream,
                       xn, wqkvgut, biasq, (void*)QKVG, ROWS, 4096, 1024, 1024,
                       16, 16, 4, 2);
    // 3. u = xn @ Bw: K-split 4 (Kslice=256, kiters=4) -> 16x4 = 64 blocks
    hipLaunchKernelGGL((mgemm64<0,true,true>), dim3(16, 4), dim3(512), 0, stream,
                       xn, wqkvgut + (size_t)4096 * 1024, (const float*)nullptr,
                       (void*)uparts, ROWS, 256, 1024, 256,
                       16, 1, 8, 1);
    // 4. u partial reduce -> ubuf bf16
    hipLaunchKernelGGL(ureduce, dim3(1024), dim3(256), 0, stream, uparts, ubuf);
    // 5. MFMA attention + chunked SSM scan, one launch
    hipLaunchKernelGGL(attn_scan, dim3(1088), dim3(256), 0, stream,
                       QKVG, ubuf, ao, A, sst, states, new_state_out);
    // 6. fused wo (split-2, bf16 partials) + cw projection, one launch
    hipLaunchKernelGGL(proj3, dim3(4, 16, 3), dim3(512), 0, stream,
                       ao, states, wot, cwt, bo, ya0b, ya1b, ys);
    // 7. gate/residual + LN2 fused -> out fp32, x2n bf16
    hipLaunchKernelGGL(fuse_ln2, dim3(ROWS), dim3(256), 0, stream,
                       x, QKVG, ya0b, ya1b, ys, ln2g, ln2b, out, x2n);
    // 8. h1 = gelu(x2n @ w1 + b1) -> bf16; 256 blocks (perfect fill)
    hipLaunchKernelGGL((mgemm64<1,true,false>), dim3(256, 1), dim3(512), 0, stream,
                       x2n, w1t, b1, (void*)h1, ROWS, 4*DD, 1024, 1024,
                       16, 16, 4, 2);
    // 9. MLP2 split-4 -> bf16 partials; 64x4 = 256 blocks (perfect fill)
    hipLaunchKernelGGL((mgemm64<0,true,true>), dim3(64, 4), dim3(512), 0, stream,
                       h1, w2t, (const float*)nullptr, (void*)parts, ROWS, DD, 4096, 1024,
                       16, 4, 8, 1);
    // 10. out += sum(partials) + b2
    hipLaunchKernelGGL(mlp2_reduce, dim3(4096), dim3(256), 0, stream, parts, b2, out);
}